// Round 1
// baseline (82.319 us; speedup 1.0000x reference)
//
#include <hip/hip_runtime.h>

#define NUM_BINS 256
#define PLANES 48                    // B*C = 16*3
#define PLANE_ELEMS (512 * 512)      // H*W
#define BPP 64                       // blocks per plane
#define CHUNK4 (PLANE_ELEMS / 4 / BPP)  // float4 per block = 1024

__global__ __launch_bounds__(256) void hist_kernel(const float* __restrict__ pred,
                                                   const float* __restrict__ target,
                                                   unsigned* __restrict__ hist) {
    __shared__ unsigned lh[4][NUM_BINS];   // per-wave private histograms
    const int t = threadIdx.x;
    for (int i = t; i < 4 * NUM_BINS; i += 256) ((unsigned*)lh)[i] = 0u;
    __syncthreads();

    const int gid   = blockIdx.x;
    const int which = gid / (PLANES * BPP);
    const int rem   = gid - which * (PLANES * BPP);
    const int plane = rem / BPP;
    const int chunk = rem - plane * BPP;

    const float* src = which ? target : pred;
    const float4* p = reinterpret_cast<const float4*>(src + (size_t)plane * PLANE_ELEMS)
                      + (size_t)chunk * CHUNK4;

    unsigned* wl = lh[t >> 6];   // this wave's private histogram

    for (int i = t; i < CHUNK4; i += 256) {
        float4 v = p[i];
        float vals[4] = {v.x, v.y, v.z, v.w};
#pragma unroll
        for (int j = 0; j < 4; ++j) {
            float x = vals[j];
            if (x >= 0.0f && x <= 1.0f) {          // values outside [0,1] ignored
                int b = (int)floorf(x * 256.0f);    // f32 multiply, matches jnp/np
                b = b > 255 ? 255 : b;              // x == 1.0 -> last bin
                atomicAdd(&wl[b], 1u);
            }
        }
    }
    __syncthreads();

    // reduce 4 wave-histograms and flush to global
    unsigned s = lh[0][t] + lh[1][t] + lh[2][t] + lh[3][t];
    if (s) atomicAdd(&hist[(size_t)(which * PLANES + plane) * NUM_BINS + t], s);
}

__global__ __launch_bounds__(256) void loss_kernel(const unsigned* __restrict__ hist,
                                                   float* __restrict__ out) {
    __shared__ unsigned ssum[2 * PLANES];
    __shared__ double sd[256];
    const int t = threadIdx.x;
    for (int i = t; i < 2 * PLANES; i += 256) ssum[i] = 0u;
    __syncthreads();

    // exact per-plane totals (integer counts, wave shuffle reduce)
    for (int p = 0; p < 2 * PLANES; ++p) {
        unsigned r = hist[(size_t)p * NUM_BINS + t];
        for (int off = 32; off; off >>= 1) r += __shfl_down(r, off, 64);
        if ((t & 63) == 0) atomicAdd(&ssum[p], r);
    }
    __syncthreads();

    // per-bin normalized diff^2, all in double (value ~3e-8, threshold ~6e-10)
    double acc = 0.0;
    for (int p = 0; p < PLANES; ++p) {
        double sp = (double)ssum[p] + 1e-8;
        double st = (double)ssum[PLANES + p] + 1e-8;
        double d  = (double)hist[(size_t)p * NUM_BINS + t] / sp
                  - (double)hist[(size_t)(PLANES + p) * NUM_BINS + t] / st;
        acc += d * d;
    }
    sd[t] = acc;
    __syncthreads();
    for (int off = 128; off; off >>= 1) {
        if (t < off) sd[t] += sd[t + off];
        __syncthreads();
    }
    if (t == 0) out[0] = (float)(sd[0] / (double)(PLANES * NUM_BINS));
}

extern "C" void kernel_launch(void* const* d_in, const int* in_sizes, int n_in,
                              void* d_out, int out_size, void* d_ws, size_t ws_size,
                              hipStream_t stream) {
    const float* pred   = (const float*)d_in[0];
    const float* target = (const float*)d_in[1];
    float* out = (float*)d_out;
    unsigned* hist = (unsigned*)d_ws;   // [2][PLANES][NUM_BINS] uint32

    hipMemsetAsync(hist, 0, (size_t)2 * PLANES * NUM_BINS * sizeof(unsigned), stream);
    hist_kernel<<<2 * PLANES * BPP, 256, 0, stream>>>(pred, target, hist);
    loss_kernel<<<1, 256, 0, stream>>>(hist, out);
}

// Round 2
// 51.651 us; speedup vs baseline: 1.5938x; 1.5938x over previous
//
#include <hip/hip_runtime.h>

#define NUM_BINS 256
#define PLANES 48                    // B*C = 16*3
#define PLANE_ELEMS (512 * 512)      // H*W
#define BPP 64                       // blocks per plane
#define CHUNK4 (PLANE_ELEMS / 4 / BPP)  // float4 per block = 1024

__global__ __launch_bounds__(256) void hist_kernel(const float* __restrict__ pred,
                                                   const float* __restrict__ target,
                                                   unsigned* __restrict__ hist,
                                                   unsigned* __restrict__ totals) {
    __shared__ unsigned lh[4][NUM_BINS];   // per-wave private histograms
    __shared__ unsigned twave[4];
    const int t = threadIdx.x;
    for (int i = t; i < 4 * NUM_BINS; i += 256) ((unsigned*)lh)[i] = 0u;
    __syncthreads();

    const int gid   = blockIdx.x;
    const int which = gid / (PLANES * BPP);
    const int rem   = gid - which * (PLANES * BPP);
    const int plane = rem / BPP;
    const int chunk = rem - plane * BPP;

    const float* src = which ? target : pred;
    const float4* p = reinterpret_cast<const float4*>(src + (size_t)plane * PLANE_ELEMS)
                      + (size_t)chunk * CHUNK4;

    unsigned* wl = lh[t >> 6];   // this wave's private histogram

    for (int i = t; i < CHUNK4; i += 256) {
        float4 v = p[i];
        float vals[4] = {v.x, v.y, v.z, v.w};
#pragma unroll
        for (int j = 0; j < 4; ++j) {
            float x = vals[j];
            if (x >= 0.0f && x <= 1.0f) {          // values outside [0,1] ignored
                int b = (int)floorf(x * 256.0f);    // f32 multiply, matches jnp/np
                b = b > 255 ? 255 : b;              // x == 1.0 -> last bin
                atomicAdd(&wl[b], 1u);
            }
        }
    }
    __syncthreads();

    // reduce 4 wave-histograms and flush to global
    unsigned s = lh[0][t] + lh[1][t] + lh[2][t] + lh[3][t];
    if (s) atomicAdd(&hist[(size_t)(which * PLANES + plane) * NUM_BINS + t], s);

    // block total (number of in-range elements this block saw) -> plane total
    unsigned bt = s;
    for (int off = 32; off; off >>= 1) bt += __shfl_down(bt, off, 64);
    if ((t & 63) == 0) twave[t >> 6] = bt;
    __syncthreads();
    if (t == 0)
        atomicAdd(&totals[which * PLANES + plane], twave[0] + twave[1] + twave[2] + twave[3]);
}

__global__ __launch_bounds__(1024) void loss_kernel(const unsigned* __restrict__ hist,
                                                    const unsigned* __restrict__ totals,
                                                    float* __restrict__ out) {
    __shared__ double inv[2 * PLANES];
    __shared__ double sd[16];
    const int t = threadIdx.x;
    if (t < 2 * PLANES) inv[t] = 1.0 / ((double)totals[t] + 1e-8);
    __syncthreads();

    // hist layout: [2][PLANES][NUM_BINS] u32. pred uint4 index i in [0,3072),
    // matching target uint4 at i + 3072. plane p = i/64.
    const uint4* h4 = reinterpret_cast<const uint4*>(hist);
    double acc = 0.0;
    for (int i = t; i < (PLANES * NUM_BINS) / 4; i += 1024) {
        uint4 hp = h4[i];
        uint4 ht = h4[i + (PLANES * NUM_BINS) / 4];
        const double ip = inv[i >> 6];
        const double it = inv[PLANES + (i >> 6)];
        double d0 = (double)hp.x * ip - (double)ht.x * it;
        double d1 = (double)hp.y * ip - (double)ht.y * it;
        double d2 = (double)hp.z * ip - (double)ht.z * it;
        double d3 = (double)hp.w * ip - (double)ht.w * it;
        acc += d0 * d0 + d1 * d1 + d2 * d2 + d3 * d3;
    }
    // wave reduce (64-wide), then 16 wave leaders via LDS
    for (int off = 32; off; off >>= 1) acc += __shfl_down(acc, off, 64);
    if ((t & 63) == 0) sd[t >> 6] = acc;
    __syncthreads();
    if (t == 0) {
        double s = 0.0;
        for (int w = 0; w < 16; ++w) s += sd[w];
        out[0] = (float)(s / (double)(PLANES * NUM_BINS));
    }
}

extern "C" void kernel_launch(void* const* d_in, const int* in_sizes, int n_in,
                              void* d_out, int out_size, void* d_ws, size_t ws_size,
                              hipStream_t stream) {
    const float* pred   = (const float*)d_in[0];
    const float* target = (const float*)d_in[1];
    float* out = (float*)d_out;
    unsigned* hist   = (unsigned*)d_ws;                          // [2][48][256] u32
    unsigned* totals = hist + (size_t)2 * PLANES * NUM_BINS;     // [96] u32

    hipMemsetAsync(d_ws, 0, ((size_t)2 * PLANES * NUM_BINS + 2 * PLANES) * sizeof(unsigned), stream);
    hist_kernel<<<2 * PLANES * BPP, 256, 0, stream>>>(pred, target, hist, totals);
    loss_kernel<<<1, 1024, 0, stream>>>(hist, totals, out);
}

// Round 3
// 46.732 us; speedup vs baseline: 1.7615x; 1.1052x over previous
//
#include <hip/hip_runtime.h>

#define NUM_BINS 256
#define PLANES 48                    // B*C = 16*3
#define PLANE_ELEMS (512 * 512)      // H*W
#define BPP 64                       // blocks per plane
#define CHUNK4 (PLANE_ELEMS / 4 / BPP)  // float4 per block = 1024
#define NHIST 16                     // sub-histograms per block (4 per wave)
#define HSTRIDE 257                  // +1 pad: bank = (h + bin) % 32

__global__ __launch_bounds__(256) void hist_kernel(const float* __restrict__ pred,
                                                   const float* __restrict__ target,
                                                   unsigned* __restrict__ hist,
                                                   unsigned* __restrict__ totals) {
    __shared__ unsigned lh[NHIST * HSTRIDE];
    __shared__ unsigned twave[4];
    const int t = threadIdx.x;
    for (int i = t; i < NHIST * HSTRIDE; i += 256) lh[i] = 0u;
    __syncthreads();

    const int gid   = blockIdx.x;
    const int which = gid / (PLANES * BPP);
    const int rem   = gid - which * (PLANES * BPP);
    const int plane = rem / BPP;
    const int chunk = rem - plane * BPP;

    const float* src = which ? target : pred;
    const float4* p = reinterpret_cast<const float4*>(src + (size_t)plane * PLANE_ELEMS)
                      + (size_t)chunk * CHUNK4;

    // wave (t>>6) owns sub-hists [4w, 4w+4); lane%4 picks one -> 16 lanes share
    unsigned* wl = lh + (size_t)(((t >> 6) << 2) + (t & 3)) * HSTRIDE;

    // 4 independent float4 loads in flight before any use
    float4 v0 = p[t];
    float4 v1 = p[t + 256];
    float4 v2 = p[t + 512];
    float4 v3 = p[t + 768];

    float vals[16] = {v0.x, v0.y, v0.z, v0.w, v1.x, v1.y, v1.z, v1.w,
                      v2.x, v2.y, v2.z, v2.w, v3.x, v3.y, v3.z, v3.w};
#pragma unroll
    for (int j = 0; j < 16; ++j) {
        float x = vals[j];
        if (x >= 0.0f && x <= 1.0f) {           // values outside [0,1] ignored
            int b = (int)(x * 256.0f);           // == floor for x >= 0
            b = b > 255 ? 255 : b;               // x == 1.0 -> last bin
            atomicAdd(&wl[b], 1u);
        }
    }
    __syncthreads();

    // bin t summed across the 16 sub-histograms, one global atomic per bin
    unsigned s = 0;
#pragma unroll
    for (int h = 0; h < NHIST; ++h) s += lh[h * HSTRIDE + t];
    if (s) atomicAdd(&hist[(size_t)(which * PLANES + plane) * NUM_BINS + t], s);

    // block total (in-range element count) -> plane total
    unsigned bt = s;
    for (int off = 32; off; off >>= 1) bt += __shfl_down(bt, off, 64);
    if ((t & 63) == 0) twave[t >> 6] = bt;
    __syncthreads();
    if (t == 0)
        atomicAdd(&totals[which * PLANES + plane], twave[0] + twave[1] + twave[2] + twave[3]);
}

__global__ __launch_bounds__(1024) void loss_kernel(const unsigned* __restrict__ hist,
                                                    const unsigned* __restrict__ totals,
                                                    float* __restrict__ out) {
    __shared__ double inv[2 * PLANES];
    __shared__ double sd[16];
    const int t = threadIdx.x;
    if (t < 2 * PLANES) inv[t] = 1.0 / ((double)totals[t] + 1e-8);
    __syncthreads();

    const uint4* h4 = reinterpret_cast<const uint4*>(hist);
    double acc = 0.0;
    for (int i = t; i < (PLANES * NUM_BINS) / 4; i += 1024) {
        uint4 hp = h4[i];
        uint4 ht = h4[i + (PLANES * NUM_BINS) / 4];
        const double ip = inv[i >> 6];
        const double it = inv[PLANES + (i >> 6)];
        double d0 = (double)hp.x * ip - (double)ht.x * it;
        double d1 = (double)hp.y * ip - (double)ht.y * it;
        double d2 = (double)hp.z * ip - (double)ht.z * it;
        double d3 = (double)hp.w * ip - (double)ht.w * it;
        acc += d0 * d0 + d1 * d1 + d2 * d2 + d3 * d3;
    }
    for (int off = 32; off; off >>= 1) acc += __shfl_down(acc, off, 64);
    if ((t & 63) == 0) sd[t >> 6] = acc;
    __syncthreads();
    if (t == 0) {
        double s = 0.0;
        for (int w = 0; w < 16; ++w) s += sd[w];
        out[0] = (float)(s / (double)(PLANES * NUM_BINS));
    }
}

extern "C" void kernel_launch(void* const* d_in, const int* in_sizes, int n_in,
                              void* d_out, int out_size, void* d_ws, size_t ws_size,
                              hipStream_t stream) {
    const float* pred   = (const float*)d_in[0];
    const float* target = (const float*)d_in[1];
    float* out = (float*)d_out;
    unsigned* hist   = (unsigned*)d_ws;                          // [2][48][256] u32
    unsigned* totals = hist + (size_t)2 * PLANES * NUM_BINS;     // [96] u32

    hipMemsetAsync(d_ws, 0, ((size_t)2 * PLANES * NUM_BINS + 2 * PLANES) * sizeof(unsigned), stream);
    hist_kernel<<<2 * PLANES * BPP, 256, 0, stream>>>(pred, target, hist, totals);
    loss_kernel<<<1, 1024, 0, stream>>>(hist, totals, out);
}